// Round 7
// baseline (77.280 us; speedup 1.0000x reference)
//
#include <hip/hip_runtime.h>
#include <hip/hip_bf16.h>

using bf16x8 = __attribute__((ext_vector_type(8))) short;
using f32x4  = __attribute__((ext_vector_type(4))) float;

#define THREADS 256
#define NBLOCKS 768
#define NWAVES  (NBLOCKS * (THREADS / 64))   // 3072
#define NTILES  31250                        // 500000 / 16
#define NITER   11                           // ceil(NTILES / NWAVES)
#define UELEMS  19200000                     // 300000 * 64
#define WS_NEED (UELEMS * 2)                 // bf16 copy of U

__device__ __forceinline__ short f2bf(float f) {
    __hip_bfloat16 h = __float2bfloat16(f);
    return __builtin_bit_cast(short, h);
}

__device__ __forceinline__ bf16x8 cvt8(float4 a, float4 b) {
    bf16x8 r;
    r[0] = f2bf(a.x); r[1] = f2bf(a.y); r[2] = f2bf(a.z); r[3] = f2bf(a.w);
    r[4] = f2bf(b.x); r[5] = f2bf(b.y); r[6] = f2bf(b.z); r[7] = f2bf(b.w);
    return r;
}

__device__ __forceinline__ void glds16(const short* g, short* l) {
    __builtin_amdgcn_global_load_lds(
        (const __attribute__((address_space(1))) void*)g,
        (__attribute__((address_space(3))) void*)l, 16, 0, 0);
}

// ---------- streaming f32 -> bf16 conversion of U into d_ws ----------
__global__ __launch_bounds__(256) void cvtU_kernel(const float* __restrict__ U,
                                                   short* __restrict__ Ub) {
    const int stride = gridDim.x * blockDim.x;
    for (int i = blockIdx.x * blockDim.x + threadIdx.x; i < UELEMS / 8; i += stride) {
        float4 a = ((const float4*)U)[2 * i];
        float4 b = ((const float4*)U)[2 * i + 1];
        ((bf16x8*)Ub)[i] = cvt8(a, b);
    }
}

// ---------- main kernel: coalesced row-gather via LDS bounce ----------
__global__ __launch_bounds__(THREADS) void etl_bf16(
    const int*   __restrict__ bi,   // [500000,3]
    const float* __restrict__ t,    // [500000]
    const short* __restrict__ Ub,   // [300000,64] bf16
    const float* __restrict__ W1,   // [193,50]
    const float* __restrict__ b1,   // [50]
    const float* __restrict__ W2,   // [50]
    const float* __restrict__ b2,   // [1]
    float*       __restrict__ out)  // [500000]
{
    __shared__ short bsh[24][64][8];                 // 24 KB: W1 B-fragments
    __shared__ __align__(16) short gbuf[4][3072];    // 24 KB: 4 waves x 48 rows x 128B

    for (int e = threadIdx.x; e < 24 * 64; e += THREADS) {
        int f = e >> 6, l = e & 63;
        int nt = f / 6, ks = f - nt * 6;
        int n  = nt * 16 + (l & 15);
        int k0 = ks * 32 + ((l >> 4) << 3);
        bf16x8 v;
#pragma unroll
        for (int j = 0; j < 8; ++j) {
            float w = (n < 50) ? W1[(k0 + j) * 50 + n] : 0.f;
            v[j] = f2bf(w);
        }
        *(bf16x8*)(&bsh[f][l][0]) = v;
    }
    __syncthreads();

    const int lane = threadIdx.x & 63;
    const int g    = lane >> 4;    // 0..3 (k-quarter within fragment)
    const int ncol = lane & 15;    // A-row within tile / n within N-tile
    const int warp = threadIdx.x >> 6;
    short* buf = &gbuf[warp][0];

    bf16x8 Bf[24];
#pragma unroll
    for (int f = 0; f < 24; ++f) Bf[f] = *(const bf16x8*)(&bsh[f][lane][0]);

    float w192[4], b1r[4], w2r[4];
#pragma unroll
    for (int nt = 0; nt < 4; ++nt) {
        int n = nt * 16 + ncol;
        bool vld = (n < 50);
        w192[nt] = vld ? W1[192 * 50 + n] : 0.f;
        b1r[nt]  = vld ? b1[n] : 0.f;
        w2r[nt]  = vld ? W2[n] : 0.f;
    }
    const float b2v = b2[0];

    const int wid = blockIdx.x * (THREADS / 64) + warp;

    auto tileAt = [&](int i) {
        int tl = wid + i * NWAVES;
        return tl < NTILES ? tl : NTILES - 1;
    };
    // one load per lane covers all 48 row-indices of a tile:
    // lane l (l<48) -> buffer row rr=l: mode=l>>4, tile-row=l&15
    auto loadIdx = [&](int i) -> int {
        int m = lane >> 4; if (m > 2) m = 2;
        int r = tileAt(i) * 16 + (lane & 15);
        return bi[r * 3 + m] + m * 100000;
    };
    // 6 x global_load_lds: instr j covers buffer rows 8j..8j+7, 8 lanes/row.
    // source chunk pre-swizzled: slot s of row rr holds chunk s ^ (rr&7).
    auto issueGather = [&](int idxv) {
#pragma unroll
        for (int j = 0; j < 6; ++j) {
            int rr    = 8 * j + (lane >> 3);
            int rowid = __shfl(idxv, rr, 64);
            const short* gp = Ub + (size_t)rowid * 64
                              + (((lane & 7) ^ (lane >> 3)) << 3);
            glds16(gp, buf + j * 512);
        }
    };
    // swizzled fragment reads: A[ks] lane: row=mode*16+ncol, chunk=h*4+g
    auto readFrags = [&](bf16x8* A) {
#pragma unroll
        for (int ks = 0; ks < 6; ++ks) {
            int mode = ks >> 1, h = ks & 1;
            int off  = (mode * 16 + ncol) * 64
                     + ((((h << 2) + g) ^ (lane & 7)) << 3);
            A[ks] = *(const bf16x8*)(buf + off);
        }
    };

    // ---------------- prologue ----------------
    bf16x8 A[6];
    int   idxv = loadIdx(0);
    issueGather(idxv);                       // tile 0 (compiler waits idxv)
    int   idx_n = loadIdx(1);
    float4 tcur = *(const float4*)(t + tileAt(0) * 16 + g * 4);

    asm volatile("s_waitcnt vmcnt(0)" ::: "memory");
    __builtin_amdgcn_sched_barrier(0);
    readFrags(A);                            // tile 0 -> regs
    asm volatile("s_waitcnt lgkmcnt(0)" ::: "memory");
    __builtin_amdgcn_sched_barrier(0);
    issueGather(idx_n);                      // tile 1 into buf (in flight)
    int   idx_n2 = loadIdx(2);
    float4 tN = *(const float4*)(t + tileAt(1) * 16 + g * 4);

    // ---------------- steady state ----------------
    for (int i = 0; i < NITER; ++i) {
        const int  tl    = wid + i * NWAVES;
        const bool valid = tl < NTILES;
        const int  base  = (valid ? tl : NTILES - 1) * 16;

        // compute tile i (A, tcur resident)
        f32x4 acc[4];
#pragma unroll
        for (int nt = 0; nt < 4; ++nt) acc[nt] = (f32x4){0.f, 0.f, 0.f, 0.f};
#pragma unroll
        for (int ks = 0; ks < 6; ++ks) {
#pragma unroll
            for (int nt = 0; nt < 4; ++nt) {
                acc[nt] = __builtin_amdgcn_mfma_f32_16x16x32_bf16(
                    A[ks], Bf[nt * 6 + ks], acc[nt], 0, 0, 0);
            }
        }

        float tarr[4] = {tcur.x, tcur.y, tcur.z, tcur.w};
        float part[4] = {0.f, 0.f, 0.f, 0.f};
#pragma unroll
        for (int nt = 0; nt < 4; ++nt) {
#pragma unroll
            for (int r = 0; r < 4; ++r) {
                float pre = acc[nt][r] + tarr[r] * w192[nt] + b1r[nt];
                float e  = __expf(2.f * pre);
                float h  = 1.f - 2.f * __builtin_amdgcn_rcpf(e + 1.f);  // tanh
                part[r] += h * w2r[nt];
            }
        }
#pragma unroll
        for (int r = 0; r < 4; ++r) {
#pragma unroll
            for (int m = 1; m < 16; m <<= 1)
                part[r] += __shfl_xor(part[r], m, 64);
        }
        const bool doStore = valid && (ncol == 0);
        float4 o = make_float4(part[0] + b2v, part[1] + b2v,
                               part[2] + b2v, part[3] + b2v);

        // pipeline advance: buf holds tile i+1 (glds issued one body ago)
        asm volatile("s_waitcnt vmcnt(0)" ::: "memory");
        __builtin_amdgcn_sched_barrier(0);
        readFrags(A);                        // tile i+1 -> regs
        asm volatile("s_waitcnt lgkmcnt(0)" ::: "memory");
        __builtin_amdgcn_sched_barrier(0);
        issueGather(idx_n2);                 // tile i+2 into buf
        idx_n2 = loadIdx(i + 3);
        tcur = tN;
        tN = *(const float4*)(t + tileAt(i + 2) * 16 + g * 4);

        if (doStore)
            *(float4*)(out + base + g * 4) = o;   // after the vmcnt drain
    }
}

// ---------- fallback: f32 gather path (ws too small) ----------
__global__ __launch_bounds__(THREADS) void etl_f32(
    const int*   __restrict__ bi,
    const float* __restrict__ t,
    const float* __restrict__ U,
    const float* __restrict__ W1,
    const float* __restrict__ b1,
    const float* __restrict__ W2,
    const float* __restrict__ b2,
    float*       __restrict__ out)
{
    __shared__ short bsh[24][64][8];
    for (int e = threadIdx.x; e < 24 * 64; e += THREADS) {
        int f = e >> 6, l = e & 63;
        int nt = f / 6, ks = f - nt * 6;
        int n  = nt * 16 + (l & 15);
        int k0 = ks * 32 + ((l >> 4) << 3);
        bf16x8 v;
#pragma unroll
        for (int j = 0; j < 8; ++j) {
            float w = (n < 50) ? W1[(k0 + j) * 50 + n] : 0.f;
            v[j] = f2bf(w);
        }
        *(bf16x8*)(&bsh[f][l][0]) = v;
    }
    __syncthreads();

    const int lane = threadIdx.x & 63;
    const int g    = lane >> 4;
    const int ncol = lane & 15;

    bf16x8 Bf[24];
#pragma unroll
    for (int f = 0; f < 24; ++f) Bf[f] = *(const bf16x8*)(&bsh[f][lane][0]);

    float w192[4], b1r[4], w2r[4];
#pragma unroll
    for (int nt = 0; nt < 4; ++nt) {
        int n = nt * 16 + ncol;
        bool vld = (n < 50);
        w192[nt] = vld ? W1[192 * 50 + n] : 0.f;
        b1r[nt]  = vld ? b1[n] : 0.f;
        w2r[nt]  = vld ? W2[n] : 0.f;
    }
    const float b2v = b2[0];

    const int nwaves = NBLOCKS * (THREADS / 64);
    const int wid    = blockIdx.x * (THREADS / 64) + (threadIdx.x >> 6);

    for (int tile = wid; tile < NTILES; tile += nwaves) {
        const int base = tile * 16;
        const int row  = base + ncol;
        int i0 = bi[row * 3 + 0];
        int i1 = bi[row * 3 + 1] + 100000;
        int i2 = bi[row * 3 + 2] + 200000;

        bf16x8 A[6];
        const float* p0 = U + (size_t)i0 * 64 + g * 8;
        const float* p1 = U + (size_t)i1 * 64 + g * 8;
        const float* p2 = U + (size_t)i2 * 64 + g * 8;
        A[0] = cvt8(((const float4*)p0)[0], ((const float4*)p0)[1]);
        A[1] = cvt8(((const float4*)(p0 + 32))[0], ((const float4*)(p0 + 32))[1]);
        A[2] = cvt8(((const float4*)p1)[0], ((const float4*)p1)[1]);
        A[3] = cvt8(((const float4*)(p1 + 32))[0], ((const float4*)(p1 + 32))[1]);
        A[4] = cvt8(((const float4*)p2)[0], ((const float4*)p2)[1]);
        A[5] = cvt8(((const float4*)(p2 + 32))[0], ((const float4*)(p2 + 32))[1]);

        f32x4 acc[4];
#pragma unroll
        for (int nt = 0; nt < 4; ++nt) acc[nt] = (f32x4){0.f, 0.f, 0.f, 0.f};
#pragma unroll
        for (int ks = 0; ks < 6; ++ks) {
#pragma unroll
            for (int nt = 0; nt < 4; ++nt) {
                acc[nt] = __builtin_amdgcn_mfma_f32_16x16x32_bf16(
                    A[ks], Bf[nt * 6 + ks], acc[nt], 0, 0, 0);
            }
        }

        float4 tv = *(const float4*)(t + base + g * 4);
        float tarr[4] = {tv.x, tv.y, tv.z, tv.w};
        float part[4] = {0.f, 0.f, 0.f, 0.f};
#pragma unroll
        for (int nt = 0; nt < 4; ++nt) {
#pragma unroll
            for (int r = 0; r < 4; ++r) {
                float pre = acc[nt][r] + tarr[r] * w192[nt] + b1r[nt];
                float e  = __expf(2.f * pre);
                float h  = 1.f - 2.f * __builtin_amdgcn_rcpf(e + 1.f);
                part[r] += h * w2r[nt];
            }
        }
#pragma unroll
        for (int r = 0; r < 4; ++r) {
#pragma unroll
            for (int m = 1; m < 16; m <<= 1)
                part[r] += __shfl_xor(part[r], m, 64);
        }
        if (ncol == 0) {
            float4 o = make_float4(part[0] + b2v, part[1] + b2v,
                                   part[2] + b2v, part[3] + b2v);
            *(float4*)(out + base + g * 4) = o;
        }
    }
}

extern "C" void kernel_launch(void* const* d_in, const int* in_sizes, int n_in,
                              void* d_out, int out_size, void* d_ws, size_t ws_size,
                              hipStream_t stream) {
    const int*   bi = (const int*)  d_in[0];
    const float* t  = (const float*)d_in[1];
    const float* U  = (const float*)d_in[2];
    const float* W1 = (const float*)d_in[3];
    const float* b1 = (const float*)d_in[4];
    const float* W2 = (const float*)d_in[5];
    const float* b2 = (const float*)d_in[6];
    float* out = (float*)d_out;

    if (ws_size >= (size_t)WS_NEED) {
        short* Ub = (short*)d_ws;
        cvtU_kernel<<<2048, 256, 0, stream>>>(U, Ub);
        etl_bf16<<<NBLOCKS, THREADS, 0, stream>>>(bi, t, Ub, W1, b1, W2, b2, out);
    } else {
        etl_f32<<<NBLOCKS, THREADS, 0, stream>>>(bi, t, U, W1, b1, W2, b2, out);
    }
}

// Round 8
// 64.907 us; speedup vs baseline: 1.1906x; 1.1906x over previous
//
#include <hip/hip_runtime.h>
#include <hip/hip_bf16.h>

using bf16x8 = __attribute__((ext_vector_type(8))) short;
using f16x8  = __attribute__((ext_vector_type(8))) _Float16;
using f32x4  = __attribute__((ext_vector_type(4))) float;

#define THREADS   256
#define NROWS_U   300000
#define WS_NEED   (NROWS_U * 64 * 2)   // V: 300000 x 64 fp16 = 38.4 MB
#define NTILES_PC 18750                // 300000 / 16
#define NB_PC     1536
#define NB_MAIN   2048
#define NITERS_M  15625                // 500000 / 32

__device__ __forceinline__ short f2bf(float f) {
    __hip_bfloat16 h = __float2bfloat16(f);
    return __builtin_bit_cast(short, h);
}

__device__ __forceinline__ bf16x8 cvt8(float4 a, float4 b) {
    bf16x8 r;
    r[0] = f2bf(a.x); r[1] = f2bf(a.y); r[2] = f2bf(a.z); r[3] = f2bf(a.w);
    r[4] = f2bf(b.x); r[5] = f2bf(b.y); r[6] = f2bf(b.z); r[7] = f2bf(b.w);
    return r;
}

// ---------------- precompute: V[r][n] = (U_mode @ W1_mode)[r][n], fp16 ----------------
// rows r in [m*100000,(m+1)*100000) use W1 k-block [m*64,(m+1)*64). n<50, pad 0.
__global__ __launch_bounds__(THREADS) void pc_kernel(
    const float* __restrict__ U,    // [300000,64]
    const float* __restrict__ W1,   // [193,50]
    _Float16*    __restrict__ V)    // [300000,64]
{
    __shared__ short bsh[24][64][8];   // [mode*8 + nt*2 + ks][lane][8]
    for (int e = threadIdx.x; e < 24 * 64; e += THREADS) {
        int f = e >> 6, l = e & 63;
        int m = f >> 3, rem = f & 7, nt = rem >> 1, ks = rem & 1;
        int n  = nt * 16 + (l & 15);
        int k0 = m * 64 + ks * 32 + ((l >> 4) << 3);
        bf16x8 v;
#pragma unroll
        for (int j = 0; j < 8; ++j) {
            float w = (n < 50) ? W1[(k0 + j) * 50 + n] : 0.f;
            v[j] = f2bf(w);
        }
        *(bf16x8*)(&bsh[f][l][0]) = v;
    }
    __syncthreads();

    const int lane = threadIdx.x & 63;
    const int g    = lane >> 4;
    const int ncol = lane & 15;
    const int nwv  = NB_PC * (THREADS / 64);

    for (int tile = blockIdx.x * (THREADS / 64) + (threadIdx.x >> 6);
         tile < NTILES_PC; tile += nwv) {
        const int mode = tile / 6250;     // 6250 tiles per mode, exact
        const int base = tile * 16;

        // A-fragments from 16 consecutive U rows (coalesced streaming)
        const float* p = U + (size_t)(base + ncol) * 64 + g * 8;
        bf16x8 A0 = cvt8(((const float4*)p)[0],        ((const float4*)p)[1]);
        bf16x8 A1 = cvt8(((const float4*)(p + 32))[0], ((const float4*)(p + 32))[1]);

        f32x4 acc[4];
#pragma unroll
        for (int nt = 0; nt < 4; ++nt) acc[nt] = (f32x4){0.f, 0.f, 0.f, 0.f};
#pragma unroll
        for (int nt = 0; nt < 4; ++nt) {
            bf16x8 B0 = *(const bf16x8*)(&bsh[mode * 8 + nt * 2 + 0][lane][0]);
            bf16x8 B1 = *(const bf16x8*)(&bsh[mode * 8 + nt * 2 + 1][lane][0]);
            acc[nt] = __builtin_amdgcn_mfma_f32_16x16x32_bf16(A0, B0, acc[nt], 0, 0, 0);
            acc[nt] = __builtin_amdgcn_mfma_f32_16x16x32_bf16(A1, B1, acc[nt], 0, 0, 0);
        }
        // D[mrow][n]: mrow = g*4 + r, n = nt*16 + ncol
#pragma unroll
        for (int r = 0; r < 4; ++r) {
#pragma unroll
            for (int nt = 0; nt < 4; ++nt) {
                V[(size_t)(base + g * 4 + r) * 64 + nt * 16 + ncol] =
                    (_Float16)acc[nt][r];
            }
        }
    }
}

// ---------------- main: gather-sum-tanh-dot over V ----------------
__global__ __launch_bounds__(THREADS) void etl_main(
    const int*      __restrict__ bi,   // [500000,3]
    const float*    __restrict__ t,    // [500000]
    const _Float16* __restrict__ V,    // [300000,64]
    const float*    __restrict__ W1,   // [193,50] (row 192 used)
    const float*    __restrict__ b1,   // [50]
    const float*    __restrict__ W2,   // [50]
    const float*    __restrict__ b2,   // [1]
    float*          __restrict__ out)  // [500000]
{
    const int lane = threadIdx.x & 63;
    const int r8   = lane >> 3;   // 0..7: row within 8-row group
    const int c    = lane & 7;    // 0..7: 8-wide column chunk (n = c*8+j)

    float w192r[8], b1r[8], w2r[8];
#pragma unroll
    for (int j = 0; j < 8; ++j) {
        int n = c * 8 + j;
        bool vld = n < 50;
        w192r[j] = vld ? W1[192 * 50 + n] : 0.f;
        b1r[j]   = vld ? b1[n] : 0.f;
        w2r[j]   = vld ? W2[n] : 0.f;
    }
    const float b2v = b2[0];

    const int nwaves = NB_MAIN * (THREADS / 64);
    for (int it = blockIdx.x * (THREADS / 64) + (threadIdx.x >> 6);
         it < NITERS_M; it += nwaves) {
        const int base = it * 32;   // 32 rows per wave-iteration

        // indices: 8 c-lanes share each address (broadcast-coalesced)
        int id[4][3];
#pragma unroll
        for (int u = 0; u < 4; ++u) {
            int r = base + u * 8 + r8;
#pragma unroll
            for (int m = 0; m < 3; ++m)
                id[u][m] = bi[r * 3 + m] + m * 100000;
        }

        // gathers: one instr = 8 rows x 128B, 8 lanes per row
        f16x8 va[4][3];
#pragma unroll
        for (int u = 0; u < 4; ++u)
#pragma unroll
            for (int m = 0; m < 3; ++m)
                va[u][m] = *(const f16x8*)(V + (size_t)id[u][m] * 64 + c * 8);

        float tv[4];
#pragma unroll
        for (int u = 0; u < 4; ++u) tv[u] = t[base + u * 8 + r8];

#pragma unroll
        for (int u = 0; u < 4; ++u) {
            float acc = 0.f;
#pragma unroll
            for (int j = 0; j < 8; ++j) {
                float h = (float)va[u][0][j] + (float)va[u][1][j] +
                          (float)va[u][2][j] + tv[u] * w192r[j] + b1r[j];
                float e = __expf(2.f * h);
                acc += (1.f - 2.f * __builtin_amdgcn_rcpf(e + 1.f)) * w2r[j];
            }
            acc += __shfl_xor(acc, 1, 64);
            acc += __shfl_xor(acc, 2, 64);
            acc += __shfl_xor(acc, 4, 64);
            if (c == 0) out[base + u * 8 + r8] = acc + b2v;
        }
    }
}

// ---------------- fallback: direct f32 gather (ws too small) ----------------
__global__ __launch_bounds__(THREADS) void etl_f32(
    const int*   __restrict__ bi,
    const float* __restrict__ t,
    const float* __restrict__ U,
    const float* __restrict__ W1,
    const float* __restrict__ b1,
    const float* __restrict__ W2,
    const float* __restrict__ b2,
    float*       __restrict__ out)
{
    __shared__ short bsh[24][64][8];
    for (int e = threadIdx.x; e < 24 * 64; e += THREADS) {
        int f = e >> 6, l = e & 63;
        int nt = f / 6, ks = f - nt * 6;
        int n  = nt * 16 + (l & 15);
        int k0 = ks * 32 + ((l >> 4) << 3);
        bf16x8 v;
#pragma unroll
        for (int j = 0; j < 8; ++j) {
            float w = (n < 50) ? W1[(k0 + j) * 50 + n] : 0.f;
            v[j] = f2bf(w);
        }
        *(bf16x8*)(&bsh[f][l][0]) = v;
    }
    __syncthreads();

    const int lane = threadIdx.x & 63;
    const int g    = lane >> 4;
    const int ncol = lane & 15;

    bf16x8 Bf[24];
#pragma unroll
    for (int f = 0; f < 24; ++f) Bf[f] = *(const bf16x8*)(&bsh[f][lane][0]);

    float w192[4], b1r[4], w2r[4];
#pragma unroll
    for (int nt = 0; nt < 4; ++nt) {
        int n = nt * 16 + ncol;
        bool vld = (n < 50);
        w192[nt] = vld ? W1[192 * 50 + n] : 0.f;
        b1r[nt]  = vld ? b1[n] : 0.f;
        w2r[nt]  = vld ? W2[n] : 0.f;
    }
    const float b2v = b2[0];

    const int nwaves = 768 * (THREADS / 64);
    const int wid    = blockIdx.x * (THREADS / 64) + (threadIdx.x >> 6);

    for (int tile = wid; tile < 31250; tile += nwaves) {
        const int base = tile * 16;
        const int row  = base + ncol;
        int i0 = bi[row * 3 + 0];
        int i1 = bi[row * 3 + 1] + 100000;
        int i2 = bi[row * 3 + 2] + 200000;

        bf16x8 A[6];
        const float* p0 = U + (size_t)i0 * 64 + g * 8;
        const float* p1 = U + (size_t)i1 * 64 + g * 8;
        const float* p2 = U + (size_t)i2 * 64 + g * 8;
        A[0] = cvt8(((const float4*)p0)[0], ((const float4*)p0)[1]);
        A[1] = cvt8(((const float4*)(p0 + 32))[0], ((const float4*)(p0 + 32))[1]);
        A[2] = cvt8(((const float4*)p1)[0], ((const float4*)p1)[1]);
        A[3] = cvt8(((const float4*)(p1 + 32))[0], ((const float4*)(p1 + 32))[1]);
        A[4] = cvt8(((const float4*)p2)[0], ((const float4*)p2)[1]);
        A[5] = cvt8(((const float4*)(p2 + 32))[0], ((const float4*)(p2 + 32))[1]);

        f32x4 acc[4];
#pragma unroll
        for (int nt = 0; nt < 4; ++nt) acc[nt] = (f32x4){0.f, 0.f, 0.f, 0.f};
#pragma unroll
        for (int ks = 0; ks < 6; ++ks) {
#pragma unroll
            for (int nt = 0; nt < 4; ++nt) {
                acc[nt] = __builtin_amdgcn_mfma_f32_16x16x32_bf16(
                    A[ks], Bf[nt * 6 + ks], acc[nt], 0, 0, 0);
            }
        }

        float4 tv = *(const float4*)(t + base + g * 4);
        float tarr[4] = {tv.x, tv.y, tv.z, tv.w};
        float part[4] = {0.f, 0.f, 0.f, 0.f};
#pragma unroll
        for (int nt = 0; nt < 4; ++nt) {
#pragma unroll
            for (int r = 0; r < 4; ++r) {
                float pre = acc[nt][r] + tarr[r] * w192[nt] + b1r[nt];
                float e  = __expf(2.f * pre);
                float h  = 1.f - 2.f * __builtin_amdgcn_rcpf(e + 1.f);
                part[r] += h * w2r[nt];
            }
        }
#pragma unroll
        for (int r = 0; r < 4; ++r) {
#pragma unroll
            for (int m = 1; m < 16; m <<= 1)
                part[r] += __shfl_xor(part[r], m, 64);
        }
        if (ncol == 0) {
            float4 o = make_float4(part[0] + b2v, part[1] + b2v,
                                   part[2] + b2v, part[3] + b2v);
            *(float4*)(out + base + g * 4) = o;
        }
    }
}

extern "C" void kernel_launch(void* const* d_in, const int* in_sizes, int n_in,
                              void* d_out, int out_size, void* d_ws, size_t ws_size,
                              hipStream_t stream) {
    const int*   bi = (const int*)  d_in[0];
    const float* t  = (const float*)d_in[1];
    const float* U  = (const float*)d_in[2];
    const float* W1 = (const float*)d_in[3];
    const float* b1 = (const float*)d_in[4];
    const float* W2 = (const float*)d_in[5];
    const float* b2 = (const float*)d_in[6];
    float* out = (float*)d_out;

    if (ws_size >= (size_t)WS_NEED) {
        _Float16* V = (_Float16*)d_ws;
        pc_kernel<<<NB_PC, THREADS, 0, stream>>>(U, W1, V);
        etl_main<<<NB_MAIN, THREADS, 0, stream>>>(bi, t, V, W1, b1, W2, b2, out);
    } else {
        etl_f32<<<768, THREADS, 0, stream>>>(bi, t, U, W1, b1, W2, b2, out);
    }
}